// Round 6
// baseline (243.932 us; speedup 1.0000x reference)
//
#include <hip/hip_runtime.h>

// Yoshida 4th-order integrator, Gamma(v) = W @ (U v)^2, B=4096, D=1024, R=256.
// Fused 3-step kernel, fp8 e4m3 MFMA path (R4 structure, M=16, VGPR~56).
// R5 lesson: launch_bounds(1024,8) -> VGPR 32 -> state spills (WRITE 216MB),
// NEVER cap below ~64 here. R4 plateau theory: all 256 blocks stream the SAME
// 512KB packed U/W in lockstep -> same-address L2 bank contention (7.9/34.5
// TB/s achieved). This round: per-block + per-wave PHASE ROTATION of both
// K-loops (sum order change only, fp32 accumulate -> numerics unchanged).
// U pre-scaled x8, W x16 at pack time (fp8 subnormal dodge), compensated in
// epilogue: h^2 = accA^2/64, Gamma = accB/16.

#define BSZ 4096
#define DD 1024
#define RR 256

typedef unsigned char uchar;
typedef long long i64;
typedef __attribute__((ext_vector_type(2))) long i64x2;
typedef __attribute__((ext_vector_type(4))) float f32x4;
typedef __attribute__((ext_vector_type(4))) unsigned int uint4v;

// pack 4 floats -> 4 fp8 e4m3 bytes (HW cvt, RNE, saturating)
__device__ inline unsigned int f2q4(float a, float b, float c, float d) {
    int lo = __builtin_amdgcn_cvt_pk_fp8_f32(a, b, 0, false);
    int hi = __builtin_amdgcn_cvt_pk_fp8_f32(c, d, lo, true);
    return (unsigned int)hi;
}
__device__ inline uchar f2q1(float x) {
    return (uchar)(__builtin_amdgcn_cvt_pk_fp8_f32(x, x, 0, false) & 0xff);
}

// ---- pack U [R,D] (x8) and W [D,R] (x16) into fragment-major fp8 -----------
// Fragment pair layout: lane l holds 16 bytes = kt=2p (k=kb..kb+7) then
// kt=2p+1 (k=kb+32..kb+39), kb = p*64 + (l>>4)*8; n = tile*16 + (l&15).
__global__ __launch_bounds__(256) void pack_uw_kernel(
    const float* __restrict__ U, const float* __restrict__ W,
    uchar* __restrict__ Upk, uchar* __restrict__ Wpk)
{
    const int g = blockIdx.x * 256 + threadIdx.x;
    const float* src;
    uchar* dst;
    float sc;
    if (g < 16384) {                       // U: 16 nt x 16 p x 64 l
        const int l = g & 63, p = (g >> 6) & 15, nt = g >> 10;
        src = U + (size_t)(nt * 16 + (l & 15)) * DD + p * 64 + (l >> 4) * 8;
        dst = Upk + ((size_t)nt << 14) + (p << 10) + (l << 4);
        sc = 8.0f;
    } else {                               // W: 64 dtile x 4 p x 64 l
        const int g2 = g - 16384;
        const int l = g2 & 63, p = (g2 >> 6) & 3, dt_ = g2 >> 8;
        src = W + (size_t)(dt_ * 16 + (l & 15)) * RR + p * 64 + (l >> 4) * 8;
        dst = Wpk + ((size_t)dt_ << 12) + (p << 10) + (l << 4);
        sc = 16.0f;
    }
    const float4 x0 = *reinterpret_cast<const float4*>(src);
    const float4 x1 = *reinterpret_cast<const float4*>(src + 4);
    const float4 y0 = *reinterpret_cast<const float4*>(src + 32);
    const float4 y1 = *reinterpret_cast<const float4*>(src + 36);
    uint4v o;
    o.x = f2q4(sc * x0.x, sc * x0.y, sc * x0.z, sc * x0.w);
    o.y = f2q4(sc * x1.x, sc * x1.y, sc * x1.z, sc * x1.w);
    o.z = f2q4(sc * y0.x, sc * y0.y, sc * y0.z, sc * y0.w);
    o.w = f2q4(sc * y1.x, sc * y1.y, sc * y1.z, sc * y1.w);
    *reinterpret_cast<uint4v*>(dst) = o;
}

// ---- fused 3-step integrator ----------------------------------------------
__global__ __launch_bounds__(1024) void yoshida_fused_kernel(
    const float* __restrict__ x_in,
    const float* __restrict__ v_in,
    const float* __restrict__ force,
    const uchar* __restrict__ Upk,
    const uchar* __restrict__ Wpk,
    float* __restrict__ x_out,
    float* __restrict__ v_out)
{
    // byte pitches 1040 / 272 (260 / 68 words, %32==4) -> near-conflict-free
    __shared__ __align__(16) uchar vS[16][1040];
    __shared__ __align__(16) uchar H2S[16][272];

    const int tid = threadIdx.x;
    const int w = tid >> 6, l = tid & 63;
    const int m = l & 15, q = l >> 4;
    const int b0 = blockIdx.x * 16;
    const int d0 = w * 64;

    // Per-block+wave K-loop phase: decorrelates the broadcast U/W stream
    // across CUs regardless of blockIdx->XCD mapping (mod-8 round-robin or
    // contiguous). Sum-order change only.
    const int ph  = (blockIdx.x + (blockIdx.x >> 3) + w) & 15;
    const int phB = ph & 3, phT = (ph >> 2) & 3;

    constexpr double CBRT2 = 1.2599210498948731647672106072782;
    constexpr double W1c = 1.0 / (2.0 - CBRT2);
    constexpr double W0c = -CBRT2 * W1c;
    constexpr double DTd = 0.01 * 1.0;
    const float dcoef[3] = {(float)(W1c * DTd), (float)(W0c * DTd), (float)(W1c * DTd)};
    const float xcoef[3] = {(float)((W0c + W1c) * 0.5), (float)((W0c + W1c) * 0.5),
                            (float)(W1c * 0.5)};
    const float c1  = (float)(W1c * 0.5);
    const float dtf = (float)DTd;

    // --- per-lane fp32 state + force in registers (MFMA C/D layout) ---------
    float vreg[16], xacc[16], freg[16];
    #pragma unroll
    for (int t = 0; t < 4; ++t)
        #pragma unroll
        for (int i = 0; i < 4; ++i) {
            const size_t gidx = (size_t)(b0 + q * 4 + i) * DD + d0 + t * 16 + m;
            const float vv = v_in[gidx];
            vreg[t * 4 + i] = vv;
            xacc[t * 4 + i] = c1 * vv;
            freg[t * 4 + i] = force[gidx];
        }

    // --- stage v tile into LDS as fp8 (thread = 16 consecutive floats) ------
    {
        const int row = tid >> 6;
        const int col = (tid & 63) * 16;
        const float* sp = v_in + (size_t)(b0 + row) * DD + col;
        const float4 f0 = *reinterpret_cast<const float4*>(sp);
        const float4 f1 = *reinterpret_cast<const float4*>(sp + 4);
        const float4 f2 = *reinterpret_cast<const float4*>(sp + 8);
        const float4 f3 = *reinterpret_cast<const float4*>(sp + 12);
        uint4v pk;
        pk.x = f2q4(f0.x, f0.y, f0.z, f0.w);
        pk.y = f2q4(f1.x, f1.y, f1.z, f1.w);
        pk.z = f2q4(f2.x, f2.y, f2.z, f2.w);
        pk.w = f2q4(f3.x, f3.y, f3.z, f3.w);
        *reinterpret_cast<uint4v*>(&vS[row][col]) = pk;
    }

    const uchar* up = Upk + ((size_t)w << 14) + (l << 4);       // wave's 16KB U
    const uchar* wp = Wpk + ((size_t)(w * 4) << 12) + (l << 4); // wave's 16KB W

    #pragma unroll
    for (int s = 0; s < 3; ++s) {
        __syncthreads();   // s==0: vS staged; s>0: epilogue vS writes visible

        // ---- GEMM A: accA = (8U) . v_q, K=1024, phase-rotated ---------------
        f32x4 a0 = {0.f, 0.f, 0.f, 0.f}, a1 = {0.f, 0.f, 0.f, 0.f};
        #pragma unroll
        for (int p = 0; p < 16; ++p) {
            const int pp = (p + ph) & 15;
            const i64x2 bb = *reinterpret_cast<const i64x2*>(up + (pp << 10));
            const i64 af0 = *reinterpret_cast<const i64*>(&vS[m][pp * 64 + q * 8]);
            const i64 af1 = *reinterpret_cast<const i64*>(&vS[m][pp * 64 + 32 + q * 8]);
            a0 = __builtin_amdgcn_mfma_f32_16x16x32_fp8_fp8(af0, bb.x, a0, 0, 0, 0);
            a1 = __builtin_amdgcn_mfma_f32_16x16x32_fp8_fp8(af1, bb.y, a1, 0, 0, 0);
        }
        #pragma unroll
        for (int i = 0; i < 4; ++i) {
            const float h8 = a0[i] + a1[i];                    // = 8*h
            H2S[q * 4 + i][w * 16 + m] = f2q1(h8 * h8 * 0.015625f);  // h^2
        }
        __syncthreads();   // H2S published

        // ---- GEMM B: accB = (16W) . h2_q, K=256, phase-rotated --------------
        f32x4 accB[4];
        #pragma unroll
        for (int t = 0; t < 4; ++t) accB[t] = (f32x4){0.f, 0.f, 0.f, 0.f};
        #pragma unroll
        for (int pi = 0; pi < 4; ++pi) {
            const int pp = (pi + phB) & 3;
            const i64 ha0 = *reinterpret_cast<const i64*>(&H2S[m][pp * 64 + q * 8]);
            const i64 ha1 = *reinterpret_cast<const i64*>(&H2S[m][pp * 64 + 32 + q * 8]);
            #pragma unroll
            for (int ti = 0; ti < 4; ++ti) {
                const int tt = (ti + phT) & 3;
                const i64x2 wb = *reinterpret_cast<const i64x2*>(wp + (tt << 12) + (pp << 10));
                accB[tt] = __builtin_amdgcn_mfma_f32_16x16x32_fp8_fp8(ha0, wb.x, accB[tt], 0, 0, 0);
                accB[tt] = __builtin_amdgcn_mfma_f32_16x16x32_fp8_fp8(ha1, wb.y, accB[tt], 0, 0, 0);
            }
        }

        // ---- epilogue: v += ddt*f - (ddt/16)*accB; xacc += cx*v; vS <- fp8(v)
        const float ddt = dcoef[s], cx = xcoef[s], gsc = dcoef[s] * 0.0625f;
        #pragma unroll
        for (int t = 0; t < 4; ++t)
            #pragma unroll
            for (int i = 0; i < 4; ++i) {
                const float vn = vreg[t * 4 + i] + ddt * freg[t * 4 + i]
                                 - gsc * accB[t][i];
                vreg[t * 4 + i] = vn;
                xacc[t * 4 + i] += cx * vn;
                vS[q * 4 + i][d0 + t * 16 + m] = f2q1(vn);
            }
    }

    // ---- final stores: x = x_in + dt*xacc; v = vreg -------------------------
    #pragma unroll
    for (int t = 0; t < 4; ++t)
        #pragma unroll
        for (int i = 0; i < 4; ++i) {
            const size_t g = (size_t)(b0 + q * 4 + i) * DD + d0 + t * 16 + m;
            x_out[g] = x_in[g] + dtf * xacc[t * 4 + i];
            v_out[g] = vreg[t * 4 + i];
        }
}

extern "C" void kernel_launch(void* const* d_in, const int* in_sizes, int n_in,
                              void* d_out, int out_size, void* d_ws, size_t ws_size,
                              hipStream_t stream) {
    const float* x     = (const float*)d_in[0];
    const float* v     = (const float*)d_in[1];
    const float* force = (const float*)d_in[2];
    const float* U     = (const float*)d_in[3];
    const float* W     = (const float*)d_in[4];

    float* x_out = (float*)d_out;
    float* v_out = x_out + (size_t)BSZ * DD;

    uchar* Upk = (uchar*)d_ws;                 // 256 KB
    uchar* Wpk = Upk + (size_t)RR * DD;        // 256 KB

    pack_uw_kernel<<<dim3(128), dim3(256), 0, stream>>>(U, W, Upk, Wpk);
    yoshida_fused_kernel<<<dim3(BSZ / 16), dim3(1024), 0, stream>>>(
        x, v, force, Upk, Wpk, x_out, v_out);
}

// Round 7
// 126.495 us; speedup vs baseline: 1.9284x; 1.9284x over previous
//
#include <hip/hip_runtime.h>

// Yoshida 4th-order integrator, Gamma(v) = W @ (U v)^2, B=4096, D=1024, R=256.
// Fused 3-step kernel, fp8 e4m3 MFMA path — EXACT R4 structure (48.5us fused,
// VGPR 56; R5/R6 showed: never cap VGPRs below ~64, never runtime-rotate the
// unrolled K-loop indices -> spills + imm-offset loss).
// R7 change: 4 physical copies of the packed U/W stream; block selects copy
// (blockIdx>>3)&3 (varies WITHIN an XCD under round-robin dispatch) to break
// the same-cache-line convoy (512 waves/XCD streaming identical lines in
// lockstep -> L2 serialization; theory from R4's 7.9/34.5 TB/s effective).
// Also: x_in folded into xacc init (removes end-of-kernel load burst).
// U pre-scaled x8, W x16 at pack (fp8 subnormal dodge); compensated exactly.

#define BSZ 4096
#define DD 1024
#define RR 256
#define NCOPY 4
#define COPY_BYTES (512u * 1024u)   // Upk (256KB) + Wpk (256KB) per copy

typedef unsigned char uchar;
typedef long long i64;
typedef __attribute__((ext_vector_type(2))) long i64x2;
typedef __attribute__((ext_vector_type(4))) float f32x4;
typedef __attribute__((ext_vector_type(4))) unsigned int uint4v;

// pack 4 floats -> 4 fp8 e4m3 bytes (HW cvt, RNE, saturating)
__device__ inline unsigned int f2q4(float a, float b, float c, float d) {
    int lo = __builtin_amdgcn_cvt_pk_fp8_f32(a, b, 0, false);
    int hi = __builtin_amdgcn_cvt_pk_fp8_f32(c, d, lo, true);
    return (unsigned int)hi;
}
__device__ inline uchar f2q1(float x) {
    return (uchar)(__builtin_amdgcn_cvt_pk_fp8_f32(x, x, 0, false) & 0xff);
}

// ---- pack U [R,D] (x8) and W [D,R] (x16) into fragment-major fp8, 4 copies -
// Fragment pair layout: lane l holds 16 bytes = kt=2p (k=kb..kb+7) then
// kt=2p+1 (k=kb+32..kb+39), kb = p*64 + (l>>4)*8; n = tile*16 + (l&15).
__global__ __launch_bounds__(256) void pack_uw_kernel(
    const float* __restrict__ U, const float* __restrict__ W,
    uchar* __restrict__ ws)
{
    const int g = blockIdx.x * 256 + threadIdx.x;
    const float* src;
    size_t off;                         // offset within one copy
    float sc;
    if (g < 16384) {                    // U: 16 nt x 16 p x 64 l
        const int l = g & 63, p = (g >> 6) & 15, nt = g >> 10;
        src = U + (size_t)(nt * 16 + (l & 15)) * DD + p * 64 + (l >> 4) * 8;
        off = ((size_t)nt << 14) + (p << 10) + (l << 4);
        sc = 8.0f;
    } else {                            // W: 64 dtile x 4 p x 64 l
        const int g2 = g - 16384;
        const int l = g2 & 63, p = (g2 >> 6) & 3, dt_ = g2 >> 8;
        src = W + (size_t)(dt_ * 16 + (l & 15)) * RR + p * 64 + (l >> 4) * 8;
        off = (size_t)(256 * 1024) + ((size_t)dt_ << 12) + (p << 10) + (l << 4);
        sc = 16.0f;
    }
    const float4 x0 = *reinterpret_cast<const float4*>(src);
    const float4 x1 = *reinterpret_cast<const float4*>(src + 4);
    const float4 y0 = *reinterpret_cast<const float4*>(src + 32);
    const float4 y1 = *reinterpret_cast<const float4*>(src + 36);
    uint4v o;
    o.x = f2q4(sc * x0.x, sc * x0.y, sc * x0.z, sc * x0.w);
    o.y = f2q4(sc * x1.x, sc * x1.y, sc * x1.z, sc * x1.w);
    o.z = f2q4(sc * y0.x, sc * y0.y, sc * y0.z, sc * y0.w);
    o.w = f2q4(sc * y1.x, sc * y1.y, sc * y1.z, sc * y1.w);
    #pragma unroll
    for (int c = 0; c < NCOPY; ++c)
        *reinterpret_cast<uint4v*>(ws + (size_t)c * COPY_BYTES + off) = o;
}

// ---- fused 3-step integrator ----------------------------------------------
__global__ __launch_bounds__(1024) void yoshida_fused_kernel(
    const float* __restrict__ x_in,
    const float* __restrict__ v_in,
    const float* __restrict__ force,
    const uchar* __restrict__ ws,
    float* __restrict__ x_out,
    float* __restrict__ v_out)
{
    // byte pitches 1040 / 272 (260 / 68 words, %32==4) -> near-conflict-free
    __shared__ __align__(16) uchar vS[16][1040];
    __shared__ __align__(16) uchar H2S[16][272];

    const int tid = threadIdx.x;
    const int w = tid >> 6, l = tid & 63;
    const int m = l & 15, q = l >> 4;
    const int b0 = blockIdx.x * 16;
    const int d0 = w * 64;

    // copy select: varies within an XCD under mod-8 round-robin dispatch
    const uchar* base = ws + (size_t)((blockIdx.x >> 3) & (NCOPY - 1)) * COPY_BYTES;

    constexpr double CBRT2 = 1.2599210498948731647672106072782;
    constexpr double W1c = 1.0 / (2.0 - CBRT2);
    constexpr double W0c = -CBRT2 * W1c;
    constexpr double DTd = 0.01 * 1.0;
    const float dcoef[3] = {(float)(W1c * DTd), (float)(W0c * DTd), (float)(W1c * DTd)};
    const float xcoef[3] = {(float)((W0c + W1c) * 0.5), (float)((W0c + W1c) * 0.5),
                            (float)(W1c * 0.5)};
    const float c1  = (float)(W1c * 0.5);
    const float dtf = (float)DTd;
    const float invdt = (float)(1.0 / DTd);

    // --- per-lane fp32 state + force in registers (MFMA C/D layout) ---------
    // xacc holds x/dt from the start (final x = dt*xacc) -> no epilogue x read
    float vreg[16], xacc[16], freg[16];
    #pragma unroll
    for (int t = 0; t < 4; ++t)
        #pragma unroll
        for (int i = 0; i < 4; ++i) {
            const size_t gidx = (size_t)(b0 + q * 4 + i) * DD + d0 + t * 16 + m;
            const float vv = v_in[gidx];
            vreg[t * 4 + i] = vv;
            xacc[t * 4 + i] = invdt * x_in[gidx] + c1 * vv;
            freg[t * 4 + i] = force[gidx];
        }

    // --- stage v tile into LDS as fp8 (thread = 16 consecutive floats) ------
    {
        const int row = tid >> 6;
        const int col = (tid & 63) * 16;
        const float* sp = v_in + (size_t)(b0 + row) * DD + col;
        const float4 f0 = *reinterpret_cast<const float4*>(sp);
        const float4 f1 = *reinterpret_cast<const float4*>(sp + 4);
        const float4 f2 = *reinterpret_cast<const float4*>(sp + 8);
        const float4 f3 = *reinterpret_cast<const float4*>(sp + 12);
        uint4v pk;
        pk.x = f2q4(f0.x, f0.y, f0.z, f0.w);
        pk.y = f2q4(f1.x, f1.y, f1.z, f1.w);
        pk.z = f2q4(f2.x, f2.y, f2.z, f2.w);
        pk.w = f2q4(f3.x, f3.y, f3.z, f3.w);
        *reinterpret_cast<uint4v*>(&vS[row][col]) = pk;
    }

    const uchar* up = base + ((size_t)w << 14) + (l << 4);          // wave's 16KB U
    const uchar* wp = base + 256 * 1024 + ((size_t)(w * 4) << 12) + (l << 4); // 16KB W

    #pragma unroll
    for (int s = 0; s < 3; ++s) {
        __syncthreads();   // s==0: vS staged; s>0: epilogue vS writes visible

        // ---- GEMM A: accA = (8U) . v_q, K=1024, 2 independent chains --------
        f32x4 a0 = {0.f, 0.f, 0.f, 0.f}, a1 = {0.f, 0.f, 0.f, 0.f};
        #pragma unroll
        for (int p = 0; p < 16; ++p) {
            const i64x2 bb = *reinterpret_cast<const i64x2*>(up + (p << 10));
            const i64 af0 = *reinterpret_cast<const i64*>(&vS[m][p * 64 + q * 8]);
            const i64 af1 = *reinterpret_cast<const i64*>(&vS[m][p * 64 + 32 + q * 8]);
            a0 = __builtin_amdgcn_mfma_f32_16x16x32_fp8_fp8(af0, bb.x, a0, 0, 0, 0);
            a1 = __builtin_amdgcn_mfma_f32_16x16x32_fp8_fp8(af1, bb.y, a1, 0, 0, 0);
        }
        #pragma unroll
        for (int i = 0; i < 4; ++i) {
            const float h8 = a0[i] + a1[i];                    // = 8*h
            H2S[q * 4 + i][w * 16 + m] = f2q1(h8 * h8 * 0.015625f);  // h^2
        }
        __syncthreads();   // H2S published

        // ---- GEMM B: accB = (16W) . h2_q, K=256 -----------------------------
        f32x4 accB[4];
        #pragma unroll
        for (int t = 0; t < 4; ++t) accB[t] = (f32x4){0.f, 0.f, 0.f, 0.f};
        #pragma unroll
        for (int p = 0; p < 4; ++p) {
            const i64 ha0 = *reinterpret_cast<const i64*>(&H2S[m][p * 64 + q * 8]);
            const i64 ha1 = *reinterpret_cast<const i64*>(&H2S[m][p * 64 + 32 + q * 8]);
            #pragma unroll
            for (int t = 0; t < 4; ++t) {
                const i64x2 wb = *reinterpret_cast<const i64x2*>(wp + (t << 12) + (p << 10));
                accB[t] = __builtin_amdgcn_mfma_f32_16x16x32_fp8_fp8(ha0, wb.x, accB[t], 0, 0, 0);
                accB[t] = __builtin_amdgcn_mfma_f32_16x16x32_fp8_fp8(ha1, wb.y, accB[t], 0, 0, 0);
            }
        }

        // ---- epilogue: v += ddt*f - (ddt/16)*accB; xacc += cx*v; vS <- fp8(v)
        const float ddt = dcoef[s], cx = xcoef[s], gsc = dcoef[s] * 0.0625f;
        #pragma unroll
        for (int t = 0; t < 4; ++t)
            #pragma unroll
            for (int i = 0; i < 4; ++i) {
                const float vn = vreg[t * 4 + i] + ddt * freg[t * 4 + i]
                                 - gsc * accB[t][i];
                vreg[t * 4 + i] = vn;
                xacc[t * 4 + i] += cx * vn;
                vS[q * 4 + i][d0 + t * 16 + m] = f2q1(vn);
            }
    }

    // ---- final stores: x = dt*xacc; v = vreg --------------------------------
    #pragma unroll
    for (int t = 0; t < 4; ++t)
        #pragma unroll
        for (int i = 0; i < 4; ++i) {
            const size_t g = (size_t)(b0 + q * 4 + i) * DD + d0 + t * 16 + m;
            x_out[g] = dtf * xacc[t * 4 + i];
            v_out[g] = vreg[t * 4 + i];
        }
}

extern "C" void kernel_launch(void* const* d_in, const int* in_sizes, int n_in,
                              void* d_out, int out_size, void* d_ws, size_t ws_size,
                              hipStream_t stream) {
    const float* x     = (const float*)d_in[0];
    const float* v     = (const float*)d_in[1];
    const float* force = (const float*)d_in[2];
    const float* U     = (const float*)d_in[3];
    const float* W     = (const float*)d_in[4];

    float* x_out = (float*)d_out;
    float* v_out = x_out + (size_t)BSZ * DD;

    uchar* ws = (uchar*)d_ws;   // NCOPY x 512KB packed copies (2 MB)

    pack_uw_kernel<<<dim3(128), dim3(256), 0, stream>>>(U, W, ws);
    yoshida_fused_kernel<<<dim3(BSZ / 16), dim3(1024), 0, stream>>>(
        x, v, force, ws, x_out, v_out);
}